// Round 2
// baseline (442.118 us; speedup 1.0000x reference)
//
#include <hip/hip_runtime.h>
#include <hip/hip_bf16.h>

#define N_NODES 50000
#define N_EDGES 800000
#define ET      (N_EDGES + N_NODES)   // edges + self loops = 850000
#define IN_DIM  128
#define HID     64
#define HEADS   4
#define C1      (HEADS * HID)         // 256
#define NEG_SLOPE 0.2f

typedef unsigned short ushort_t;

__device__ __forceinline__ float bf2f(ushort_t u) {
    union { unsigned int i; float f; } c; c.i = ((unsigned int)u) << 16; return c.f;
}
__device__ __forceinline__ ushort_t f2bf(float f) {
    union { float f; unsigned int i; } c; c.f = f;
    unsigned int r = c.i + 0x7fffu + ((c.i >> 16) & 1u);   // RNE
    return (ushort_t)(r >> 16);
}
__device__ __forceinline__ float lrelu(float x) { return x > 0.f ? x : NEG_SLOPE * x; }

__device__ __forceinline__ float wave_max(float v) {
    #pragma unroll
    for (int off = 32; off > 0; off >>= 1) v = fmaxf(v, __shfl_xor(v, off, 64));
    return v;
}
__device__ __forceinline__ float wave_sum(float v) {
    #pragma unroll
    for (int off = 32; off > 0; off >>= 1) v += __shfl_xor(v, off, 64);
    return v;
}

// ---------------- edge_index width detector ----------------
// If edge_index is int64 on device, the high word of every element is 0
// (node ids < 50000). Genuine int32 data has random node ids at odd words.
__global__ void k_detect64(const int* __restrict__ ei, int* __restrict__ flag) {
    if (threadIdx.x == 0 && blockIdx.x == 0) {
        int z = 1;
        for (int i = 1; i < 64; i += 2) if (ei[i] != 0) z = 0;
        *flag = z;
    }
}

__device__ __forceinline__ int load_idx(const int* ei, int elem, int is64) {
    return is64 ? ei[2 * elem] : ei[elem];   // little-endian low word
}

// ---------------- CSR build ----------------
__global__ void k_init_deg(int* __restrict__ deg) {
    int i = blockIdx.x * 256 + threadIdx.x;
    if (i < N_NODES) deg[i] = 1;   // self-loop
}

__global__ void k_count(const int* __restrict__ ei, const int* __restrict__ flag,
                        int* __restrict__ deg) {
    int i = blockIdx.x * 256 + threadIdx.x;
    if (i < N_EDGES) {
        int d = load_idx(ei, N_EDGES + i, *flag);
        atomicAdd(&deg[d], 1);
    }
}

__global__ __launch_bounds__(1024) void k_scan(const int* __restrict__ deg,
                                               int* __restrict__ row_start,
                                               int* __restrict__ cursor) {
    __shared__ int wsum[16];
    __shared__ int chunk_tot;
    __shared__ int running_s;
    int tid = threadIdx.x, lane = tid & 63, wid = tid >> 6;
    if (tid == 0) running_s = 0;
    __syncthreads();
    const int nchunk = (N_NODES + 1023) / 1024;
    for (int c = 0; c < nchunk; ++c) {
        int idx = c * 1024 + tid;
        int v = (idx < N_NODES) ? deg[idx] : 0;
        int x = v;
        #pragma unroll
        for (int off = 1; off < 64; off <<= 1) {
            int t = __shfl_up(x, off, 64);
            if (lane >= off) x += t;
        }
        if (lane == 63) wsum[wid] = x;
        __syncthreads();
        int base = running_s;
        if (tid == 0) {
            int a = 0;
            for (int w = 0; w < 16; ++w) { int t = wsum[w]; wsum[w] = a; a += t; }
            chunk_tot = a;
        }
        __syncthreads();
        int excl = base + wsum[wid] + (x - v);
        if (idx < N_NODES) { row_start[idx] = excl; cursor[idx] = excl; }
        __syncthreads();
        if (tid == 0) running_s = base + chunk_tot;
        __syncthreads();
    }
    if (tid == 0) row_start[N_NODES] = running_s;
}

__global__ void k_scatter(const int* __restrict__ ei, const int* __restrict__ flag,
                          int* __restrict__ cursor, int* __restrict__ edge_src) {
    int i = blockIdx.x * 256 + threadIdx.x;
    if (i >= ET) return;
    int s, d;
    if (i < N_EDGES) {
        int f = *flag;
        s = load_idx(ei, i, f);
        d = load_idx(ei, N_EDGES + i, f);
    } else {
        s = d = i - N_EDGES;
    }
    int pos = atomicAdd(&cursor[d], 1);
    edge_src[pos] = s;
}

// ---------------- Layer 1 GEMM: h1 = x @ W1  (fp32 in, fp32 acc, bf16 out) ----------------
__global__ __launch_bounds__(256) void k_gemm1(const float* __restrict__ x,
                                               const float* __restrict__ W1,
                                               ushort_t* __restrict__ h1) {
    __shared__ float As[64][68];   // padded: kills 4-way bank conflict on row-column reads
    __shared__ float Bs[64][64];
    int tid = threadIdx.x;
    int tx = tid & 15, ty = tid >> 4;
    int row0 = blockIdx.x * 64, col0 = blockIdx.y * 64;
    float acc[4][4] = {{0.f}};
    for (int kc = 0; kc < 2; ++kc) {
        #pragma unroll
        for (int it = 0; it < 4; ++it) {
            int e = (it * 256 + tid) * 4;
            int r = e >> 6, k = e & 63;
            int row = row0 + r;
            float4 av = make_float4(0.f, 0.f, 0.f, 0.f);
            if (row < N_NODES) av = *(const float4*)(x + row * IN_DIM + kc * 64 + k);
            *(float4*)&As[r][k] = av;
            *(float4*)&Bs[r][k] = *(const float4*)(W1 + (kc * 64 + r) * C1 + col0 + k);
        }
        __syncthreads();
        #pragma unroll 4
        for (int k = 0; k < 64; k += 4) {
            float a[4][4], b[4][4];
            #pragma unroll
            for (int i2 = 0; i2 < 4; ++i2) *(float4*)a[i2] = *(const float4*)&As[ty * 4 + i2][k];
            #pragma unroll
            for (int kk = 0; kk < 4; ++kk) *(float4*)b[kk] = *(const float4*)&Bs[k + kk][tx * 4];
            #pragma unroll
            for (int i2 = 0; i2 < 4; ++i2)
                #pragma unroll
                for (int j = 0; j < 4; ++j)
                    acc[i2][j] += a[i2][0] * b[0][j] + a[i2][1] * b[1][j]
                                + a[i2][2] * b[2][j] + a[i2][3] * b[3][j];
        }
        __syncthreads();
    }
    #pragma unroll
    for (int i2 = 0; i2 < 4; ++i2) {
        int row = row0 + ty * 4 + i2;
        if (row < N_NODES) {
            ushort4 hv;
            hv.x = f2bf(acc[i2][0]); hv.y = f2bf(acc[i2][1]);
            hv.z = f2bf(acc[i2][2]); hv.w = f2bf(acc[i2][3]);
            *(ushort4*)&h1[row * C1 + col0 + tx * 4] = hv;
        }
    }
}

// ---------------- Layer 1 attention logits ----------------
__global__ __launch_bounds__(256) void k_alpha1(const ushort_t* __restrict__ h1,
                                                const float* __restrict__ a_src,
                                                const float* __restrict__ a_dst,
                                                float* __restrict__ as1,
                                                float* __restrict__ ad1) {
    int lane = threadIdx.x & 63;
    int node = blockIdx.x * 4 + (threadIdx.x >> 6);
    float ps[4], pd[4];
    #pragma unroll
    for (int h = 0; h < 4; ++h) {
        float hv = bf2f(h1[node * C1 + h * 64 + lane]);
        ps[h] = hv * a_src[h * 64 + lane];
        pd[h] = hv * a_dst[h * 64 + lane];
    }
    #pragma unroll
    for (int h = 0; h < 4; ++h) { ps[h] = wave_sum(ps[h]); pd[h] = wave_sum(pd[h]); }
    if (lane == 0) {
        #pragma unroll
        for (int h = 0; h < 4; ++h) { as1[node * 4 + h] = ps[h]; ad1[node * 4 + h] = pd[h]; }
    }
}

// ---------------- Layer 1 segment softmax + aggregation (+bias, ReLU) ----------------
__global__ __launch_bounds__(256) void k_agg1(const ushort_t* __restrict__ h1,
                                              const float* __restrict__ as1,
                                              const float* __restrict__ ad1,
                                              const int* __restrict__ row_start,
                                              const int* __restrict__ edge_src,
                                              const float* __restrict__ b1,
                                              ushort_t* __restrict__ out1) {
    int lane = threadIdx.x & 63;
    int node = blockIdx.x * 4 + (threadIdx.x >> 6);
    int rs = row_start[node], re = row_start[node + 1];
    float ad[4];
    #pragma unroll
    for (int h = 0; h < 4; ++h) ad[h] = ad1[node * 4 + h];
    float mx[4] = {-1e30f, -1e30f, -1e30f, -1e30f};
    for (int i = rs + lane; i < re; i += 64) {
        int s = edge_src[i];
        float4 av = *(const float4*)&as1[s * 4];
        mx[0] = fmaxf(mx[0], lrelu(av.x + ad[0]));
        mx[1] = fmaxf(mx[1], lrelu(av.y + ad[1]));
        mx[2] = fmaxf(mx[2], lrelu(av.z + ad[2]));
        mx[3] = fmaxf(mx[3], lrelu(av.w + ad[3]));
    }
    #pragma unroll
    for (int h = 0; h < 4; ++h) mx[h] = wave_max(mx[h]);
    float acc[4] = {0.f, 0.f, 0.f, 0.f};
    float den[4] = {0.f, 0.f, 0.f, 0.f};
    for (int i = rs; i < re; ++i) {
        int s = edge_src[i];                       // broadcast load
        float4 av = *(const float4*)&as1[s * 4];   // broadcast load
        float w0 = __expf(lrelu(av.x + ad[0]) - mx[0]); den[0] += w0;
        float w1 = __expf(lrelu(av.y + ad[1]) - mx[1]); den[1] += w1;
        float w2 = __expf(lrelu(av.z + ad[2]) - mx[2]); den[2] += w2;
        float w3 = __expf(lrelu(av.w + ad[3]) - mx[3]); den[3] += w3;
        const ushort_t* hp = h1 + (size_t)s * C1;  // coalesced 128B per head
        acc[0] += w0 * bf2f(hp[lane]);
        acc[1] += w1 * bf2f(hp[64 + lane]);
        acc[2] += w2 * bf2f(hp[128 + lane]);
        acc[3] += w3 * bf2f(hp[192 + lane]);
    }
    #pragma unroll
    for (int h = 0; h < 4; ++h) {
        float o = acc[h] / (den[h] + 1e-16f) + b1[h * 64 + lane];
        out1[node * C1 + h * 64 + lane] = f2bf(fmaxf(o, 0.f));   // + b1, ReLU
    }
}

// ---------------- Layer 2 projection + logits ----------------
__global__ __launch_bounds__(256) void k_l2a(const ushort_t* __restrict__ out1,
                                             const float* __restrict__ W2,
                                             const float* __restrict__ a_src2,
                                             const float* __restrict__ a_dst2,
                                             float* __restrict__ h2,
                                             float* __restrict__ as2,
                                             float* __restrict__ ad2) {
    int lane = threadIdx.x & 63;
    int node = blockIdx.x * 4 + (threadIdx.x >> 6);
    float sum = 0.f;
    #pragma unroll
    for (int h = 0; h < 4; ++h) {
        int c = h * 64 + lane;
        sum += bf2f(out1[node * C1 + c]) * W2[c];
    }
    sum = wave_sum(sum);
    if (lane == 0) {
        h2[node]  = sum;
        as2[node] = sum * a_src2[0];
        ad2[node] = sum * a_dst2[0];
    }
}

// ---------------- Layer 2 segment softmax + aggregation + sigmoid ----------------
__global__ __launch_bounds__(256) void k_agg2(const float* __restrict__ h2,
                                              const float* __restrict__ as2,
                                              const float* __restrict__ ad2,
                                              const int* __restrict__ row_start,
                                              const int* __restrict__ edge_src,
                                              const float* __restrict__ b2,
                                              float* __restrict__ outp) {
    int lane = threadIdx.x & 63;
    int node = blockIdx.x * 4 + (threadIdx.x >> 6);
    int rs = row_start[node], re = row_start[node + 1];
    float adv = ad2[node];
    float mx = -1e30f;
    for (int i = rs + lane; i < re; i += 64) {
        int s = edge_src[i];
        mx = fmaxf(mx, lrelu(as2[s] + adv));
    }
    mx = wave_max(mx);
    float se = 0.f, wsm = 0.f;
    for (int i = rs + lane; i < re; i += 64) {
        int s = edge_src[i];
        float w = __expf(lrelu(as2[s] + adv) - mx);
        se += w; wsm += w * h2[s];
    }
    se = wave_sum(se); wsm = wave_sum(wsm);
    if (lane == 0) {
        float v = wsm / (se + 1e-16f) + b2[0];
        outp[node] = 1.f / (1.f + __expf(-v));
    }
}

extern "C" void kernel_launch(void* const* d_in, const int* in_sizes, int n_in,
                              void* d_out, int out_size, void* d_ws, size_t ws_size,
                              hipStream_t stream) {
    (void)in_sizes; (void)n_in; (void)out_size; (void)ws_size;
    const float* x      = (const float*)d_in[0];
    const int*   ei     = (const int*)  d_in[1];
    const float* W1     = (const float*)d_in[2];
    const float* a_src1 = (const float*)d_in[3];
    const float* a_dst1 = (const float*)d_in[4];
    const float* b1     = (const float*)d_in[5];
    const float* W2     = (const float*)d_in[6];
    const float* a_src2 = (const float*)d_in[7];
    const float* a_dst2 = (const float*)d_in[8];
    const float* b2     = (const float*)d_in[9];
    float* out = (float*)d_out;

    char* w = (char*)d_ws;
    size_t off = 0;
    auto alloc = [&](size_t bytes) {
        void* p = w + off; off += (bytes + 255) & ~(size_t)255; return p;
    };
    ushort_t* h1       = (ushort_t*)alloc((size_t)N_NODES * C1 * 2);
    ushort_t* out1     = (ushort_t*)alloc((size_t)N_NODES * C1 * 2);
    float*    as1      = (float*)   alloc((size_t)N_NODES * 4 * 4);
    float*    ad1      = (float*)   alloc((size_t)N_NODES * 4 * 4);
    float*    h2       = (float*)   alloc((size_t)N_NODES * 4);
    float*    as2      = (float*)   alloc((size_t)N_NODES * 4);
    float*    ad2      = (float*)   alloc((size_t)N_NODES * 4);
    int*      row_start= (int*)     alloc((size_t)(N_NODES + 1) * 4);
    int*      deg      = (int*)     alloc((size_t)N_NODES * 4);
    int*      cursor   = (int*)     alloc((size_t)N_NODES * 4);
    int*      edge_src = (int*)     alloc((size_t)ET * 4);
    int*      flag64   = (int*)     alloc(4);

    k_detect64<<<1, 64, 0, stream>>>(ei, flag64);
    k_init_deg<<<(N_NODES + 255) / 256, 256, 0, stream>>>(deg);
    k_count<<<(N_EDGES + 255) / 256, 256, 0, stream>>>(ei, flag64, deg);
    k_scan<<<1, 1024, 0, stream>>>(deg, row_start, cursor);
    k_scatter<<<(ET + 255) / 256, 256, 0, stream>>>(ei, flag64, cursor, edge_src);

    dim3 g1((N_NODES + 63) / 64, C1 / 64);
    k_gemm1<<<g1, 256, 0, stream>>>(x, W1, h1);
    k_alpha1<<<N_NODES / 4, 256, 0, stream>>>(h1, a_src1, a_dst1, as1, ad1);
    k_agg1<<<N_NODES / 4, 256, 0, stream>>>(h1, as1, ad1, row_start, edge_src, b1, out1);
    k_l2a<<<N_NODES / 4, 256, 0, stream>>>(out1, W2, a_src2, a_dst2, h2, as2, ad2);
    k_agg2<<<N_NODES / 4, 256, 0, stream>>>(h2, as2, ad2, row_start, edge_src, b2, out);
}

// Round 3
// 405.933 us; speedup vs baseline: 1.0891x; 1.0891x over previous
//
#include <hip/hip_runtime.h>
#include <hip/hip_bf16.h>

#define N_NODES 50000
#define N_EDGES 800000
#define ET      (N_EDGES + N_NODES)   // edges + self loops = 850000
#define IN_DIM  128
#define HID     64
#define HEADS   4
#define C1      (HEADS * HID)         // 256
#define NEG_SLOPE 0.2f

typedef unsigned short ushort_t;

__device__ __forceinline__ float bf2f(ushort_t u) {
    union { unsigned int i; float f; } c; c.i = ((unsigned int)u) << 16; return c.f;
}
__device__ __forceinline__ ushort_t f2bf(float f) {
    union { float f; unsigned int i; } c; c.f = f;
    unsigned int r = c.i + 0x7fffu + ((c.i >> 16) & 1u);   // RNE
    return (ushort_t)(r >> 16);
}
__device__ __forceinline__ float lrelu(float x) { return x > 0.f ? x : NEG_SLOPE * x; }

__device__ __forceinline__ float wave_max(float v) {
    #pragma unroll
    for (int off = 32; off > 0; off >>= 1) v = fmaxf(v, __shfl_xor(v, off, 64));
    return v;
}
__device__ __forceinline__ float wave_sum(float v) {
    #pragma unroll
    for (int off = 32; off > 0; off >>= 1) v += __shfl_xor(v, off, 64);
    return v;
}

__device__ __forceinline__ int load_idx(const int* ei, int elem, int is64) {
    return is64 ? ei[2 * elem] : ei[elem];   // little-endian low word
}

// ---------------- CSR build ----------------
// Also detects whether edge_index arrived as int64 (high words all zero).
__global__ void k_init_deg(const int* __restrict__ ei, int* __restrict__ deg,
                           int* __restrict__ flag) {
    int i = blockIdx.x * 256 + threadIdx.x;
    if (i < N_NODES) deg[i] = 1;   // self-loop
    if (i == 0) {
        int z = 1;
        for (int k = 1; k < 64; k += 2) if (ei[k] != 0) z = 0;
        *flag = z;
    }
}

__global__ void k_count(const int* __restrict__ ei, const int* __restrict__ flag,
                        int* __restrict__ deg) {
    int i = blockIdx.x * 256 + threadIdx.x;
    if (i < N_EDGES) {
        int d = load_idx(ei, N_EDGES + i, *flag);
        atomicAdd(&deg[d], 1);
    }
}

__global__ __launch_bounds__(1024) void k_scan(const int* __restrict__ deg,
                                               int* __restrict__ row_start,
                                               int* __restrict__ cursor) {
    __shared__ int wsum[16];
    __shared__ int chunk_tot;
    __shared__ int running_s;
    int tid = threadIdx.x, lane = tid & 63, wid = tid >> 6;
    if (tid == 0) running_s = 0;
    __syncthreads();
    const int nchunk = (N_NODES + 1023) / 1024;
    for (int c = 0; c < nchunk; ++c) {
        int idx = c * 1024 + tid;
        int v = (idx < N_NODES) ? deg[idx] : 0;
        int x = v;
        #pragma unroll
        for (int off = 1; off < 64; off <<= 1) {
            int t = __shfl_up(x, off, 64);
            if (lane >= off) x += t;
        }
        if (lane == 63) wsum[wid] = x;
        __syncthreads();
        int base = running_s;
        if (tid == 0) {
            int a = 0;
            for (int w = 0; w < 16; ++w) { int t = wsum[w]; wsum[w] = a; a += t; }
            chunk_tot = a;
        }
        __syncthreads();
        int excl = base + wsum[wid] + (x - v);
        if (idx < N_NODES) { row_start[idx] = excl; cursor[idx] = excl; }
        __syncthreads();
        if (tid == 0) running_s = base + chunk_tot;
        __syncthreads();
    }
    if (tid == 0) row_start[N_NODES] = running_s;
}

__global__ void k_scatter(const int* __restrict__ ei, const int* __restrict__ flag,
                          int* __restrict__ cursor, int* __restrict__ edge_src) {
    int i = blockIdx.x * 256 + threadIdx.x;
    if (i >= ET) return;
    int s, d;
    if (i < N_EDGES) {
        int f = *flag;
        s = load_idx(ei, i, f);
        d = load_idx(ei, N_EDGES + i, f);
    } else {
        s = d = i - N_EDGES;
    }
    int pos = atomicAdd(&cursor[d], 1);
    edge_src[pos] = s;
}

// ---------------- Layer 1 GEMM: h1 = x @ W1  (fp32 in, fp32 acc, bf16 out) ----------------
__global__ __launch_bounds__(256) void k_gemm1(const float* __restrict__ x,
                                               const float* __restrict__ W1,
                                               ushort_t* __restrict__ h1) {
    __shared__ float As[64][68];   // padded: kills 4-way bank conflict
    __shared__ float Bs[64][64];
    int tid = threadIdx.x;
    int tx = tid & 15, ty = tid >> 4;
    int row0 = blockIdx.x * 64, col0 = blockIdx.y * 64;
    float acc[4][4] = {{0.f}};
    for (int kc = 0; kc < 2; ++kc) {
        #pragma unroll
        for (int it = 0; it < 4; ++it) {
            int e = (it * 256 + tid) * 4;
            int r = e >> 6, k = e & 63;
            int row = row0 + r;
            float4 av = make_float4(0.f, 0.f, 0.f, 0.f);
            if (row < N_NODES) av = *(const float4*)(x + row * IN_DIM + kc * 64 + k);
            *(float4*)&As[r][k] = av;
            *(float4*)&Bs[r][k] = *(const float4*)(W1 + (kc * 64 + r) * C1 + col0 + k);
        }
        __syncthreads();
        #pragma unroll 4
        for (int k = 0; k < 64; k += 4) {
            float a[4][4], b[4][4];
            #pragma unroll
            for (int i2 = 0; i2 < 4; ++i2) *(float4*)a[i2] = *(const float4*)&As[ty * 4 + i2][k];
            #pragma unroll
            for (int kk = 0; kk < 4; ++kk) *(float4*)b[kk] = *(const float4*)&Bs[k + kk][tx * 4];
            #pragma unroll
            for (int i2 = 0; i2 < 4; ++i2)
                #pragma unroll
                for (int j = 0; j < 4; ++j)
                    acc[i2][j] += a[i2][0] * b[0][j] + a[i2][1] * b[1][j]
                                + a[i2][2] * b[2][j] + a[i2][3] * b[3][j];
        }
        __syncthreads();
    }
    #pragma unroll
    for (int i2 = 0; i2 < 4; ++i2) {
        int row = row0 + ty * 4 + i2;
        if (row < N_NODES) {
            ushort4 hv;
            hv.x = f2bf(acc[i2][0]); hv.y = f2bf(acc[i2][1]);
            hv.z = f2bf(acc[i2][2]); hv.w = f2bf(acc[i2][3]);
            *(ushort4*)&h1[row * C1 + col0 + tx * 4] = hv;
        }
    }
}

// ---------------- Layer 1 attention logits ----------------
__global__ __launch_bounds__(256) void k_alpha1(const ushort_t* __restrict__ h1,
                                                const float* __restrict__ a_src,
                                                const float* __restrict__ a_dst,
                                                float* __restrict__ as1,
                                                float* __restrict__ ad1) {
    int lane = threadIdx.x & 63;
    int node = blockIdx.x * 4 + (threadIdx.x >> 6);
    float ps[4], pd[4];
    #pragma unroll
    for (int h = 0; h < 4; ++h) {
        float hv = bf2f(h1[node * C1 + h * 64 + lane]);
        ps[h] = hv * a_src[h * 64 + lane];
        pd[h] = hv * a_dst[h * 64 + lane];
    }
    #pragma unroll
    for (int h = 0; h < 4; ++h) { ps[h] = wave_sum(ps[h]); pd[h] = wave_sum(pd[h]); }
    if (lane == 0) {
        #pragma unroll
        for (int h = 0; h < 4; ++h) { as1[node * 4 + h] = ps[h]; ad1[node * 4 + h] = pd[h]; }
    }
}

// ---------------- Layer 1 segment softmax + aggregation (+bias, ReLU) ----------------
// Chunked two-phase: weights computed ONCE per edge (lane-parallel), staged in
// a per-wave LDS slot; gather pass reads the whole 256-col h1 row as one
// ushort4 per lane (512 B / wave / edge, single transaction).
__global__ __launch_bounds__(256) void k_agg1(const ushort_t* __restrict__ h1,
                                              const float* __restrict__ as1,
                                              const float* __restrict__ ad1,
                                              const int* __restrict__ row_start,
                                              const int* __restrict__ edge_src,
                                              const float* __restrict__ b1,
                                              ushort_t* __restrict__ out1) {
    __shared__ float wbuf[4][64][4];   // [wave][chunk-pos][head] — broadcast reads, conflict-free
    int lane = threadIdx.x & 63;
    int wid  = threadIdx.x >> 6;
    int node = blockIdx.x * 4 + wid;
    int rs = row_start[node], re = row_start[node + 1];
    float4 ad = *(const float4*)&ad1[node * 4];

    // pass 1: per-head max over in-edges (strided)
    float4 mx = make_float4(-1e30f, -1e30f, -1e30f, -1e30f);
    for (int i = rs + lane; i < re; i += 64) {
        int s = edge_src[i];
        float4 av = *(const float4*)&as1[s * 4];
        mx.x = fmaxf(mx.x, lrelu(av.x + ad.x));
        mx.y = fmaxf(mx.y, lrelu(av.y + ad.y));
        mx.z = fmaxf(mx.z, lrelu(av.z + ad.z));
        mx.w = fmaxf(mx.w, lrelu(av.w + ad.w));
    }
    mx.x = wave_max(mx.x); mx.y = wave_max(mx.y);
    mx.z = wave_max(mx.z); mx.w = wave_max(mx.w);

    const int head = lane >> 4;
    float4 acc = make_float4(0.f, 0.f, 0.f, 0.f);
    float4 den = make_float4(0.f, 0.f, 0.f, 0.f);

    for (int base = rs; base < re; base += 64) {
        int i = base + lane;
        int s_l = 0;
        float4 w = make_float4(0.f, 0.f, 0.f, 0.f);
        if (i < re) {
            s_l = edge_src[i];
            float4 av = *(const float4*)&as1[s_l * 4];
            w.x = __expf(lrelu(av.x + ad.x) - mx.x);
            w.y = __expf(lrelu(av.y + ad.y) - mx.y);
            w.z = __expf(lrelu(av.z + ad.z) - mx.z);
            w.w = __expf(lrelu(av.w + ad.w) - mx.w);
        }
        den.x += w.x; den.y += w.y; den.z += w.z; den.w += w.w;
        *(float4*)&wbuf[wid][lane][0] = w;     // per-wave slot; in-wave lgkmcnt ordering
        int m = re - base; if (m > 64) m = 64;
        for (int j = 0; j < m; ++j) {
            int s = __shfl(s_l, j, 64);                        // uniform idx -> readlane
            float wgt = wbuf[wid][j][head];                    // 16-way broadcast read
            const ushort_t* hp = h1 + (size_t)s * C1 + lane * 4;
            ushort4 hv = *(const ushort4*)hp;                  // 8 B/lane, 512 B/wave
            acc.x += wgt * bf2f(hv.x);
            acc.y += wgt * bf2f(hv.y);
            acc.z += wgt * bf2f(hv.z);
            acc.w += wgt * bf2f(hv.w);
        }
    }

    float d0 = wave_sum(den.x), d1 = wave_sum(den.y);
    float d2 = wave_sum(den.z), d3 = wave_sum(den.w);
    float dh = head == 0 ? d0 : head == 1 ? d1 : head == 2 ? d2 : d3;
    float inv = 1.f / (dh + 1e-16f);
    float4 bv = *(const float4*)&b1[lane * 4];
    ushort4 o;
    o.x = f2bf(fmaxf(acc.x * inv + bv.x, 0.f));
    o.y = f2bf(fmaxf(acc.y * inv + bv.y, 0.f));
    o.z = f2bf(fmaxf(acc.z * inv + bv.z, 0.f));
    o.w = f2bf(fmaxf(acc.w * inv + bv.w, 0.f));
    *(ushort4*)&out1[(size_t)node * C1 + lane * 4] = o;
}

// ---------------- Layer 2 projection + logits ----------------
__global__ __launch_bounds__(256) void k_l2a(const ushort_t* __restrict__ out1,
                                             const float* __restrict__ W2,
                                             const float* __restrict__ a_src2,
                                             const float* __restrict__ a_dst2,
                                             float* __restrict__ h2,
                                             float* __restrict__ as2,
                                             float* __restrict__ ad2) {
    int lane = threadIdx.x & 63;
    int node = blockIdx.x * 4 + (threadIdx.x >> 6);
    float4 wv = *(const float4*)&W2[lane * 4];
    ushort4 ov = *(const ushort4*)&out1[(size_t)node * C1 + lane * 4];
    float sum = bf2f(ov.x) * wv.x + bf2f(ov.y) * wv.y
              + bf2f(ov.z) * wv.z + bf2f(ov.w) * wv.w;
    sum = wave_sum(sum);
    if (lane == 0) {
        h2[node]  = sum;
        as2[node] = sum * a_src2[0];
        ad2[node] = sum * a_dst2[0];
    }
}

// ---------------- Layer 2 segment softmax + aggregation + sigmoid ----------------
__global__ __launch_bounds__(256) void k_agg2(const float* __restrict__ h2,
                                              const float* __restrict__ as2,
                                              const float* __restrict__ ad2,
                                              const int* __restrict__ row_start,
                                              const int* __restrict__ edge_src,
                                              const float* __restrict__ b2,
                                              float* __restrict__ outp) {
    int lane = threadIdx.x & 63;
    int node = blockIdx.x * 4 + (threadIdx.x >> 6);
    int rs = row_start[node], re = row_start[node + 1];
    float adv = ad2[node];
    float mx = -1e30f;
    for (int i = rs + lane; i < re; i += 64) {
        int s = edge_src[i];
        mx = fmaxf(mx, lrelu(as2[s] + adv));
    }
    mx = wave_max(mx);
    float se = 0.f, wsm = 0.f;
    for (int i = rs + lane; i < re; i += 64) {
        int s = edge_src[i];
        float w = __expf(lrelu(as2[s] + adv) - mx);
        se += w; wsm += w * h2[s];
    }
    se = wave_sum(se); wsm = wave_sum(wsm);
    if (lane == 0) {
        float v = wsm / (se + 1e-16f) + b2[0];
        outp[node] = 1.f / (1.f + __expf(-v));
    }
}

extern "C" void kernel_launch(void* const* d_in, const int* in_sizes, int n_in,
                              void* d_out, int out_size, void* d_ws, size_t ws_size,
                              hipStream_t stream) {
    (void)in_sizes; (void)n_in; (void)out_size; (void)ws_size;
    const float* x      = (const float*)d_in[0];
    const int*   ei     = (const int*)  d_in[1];
    const float* W1     = (const float*)d_in[2];
    const float* a_src1 = (const float*)d_in[3];
    const float* a_dst1 = (const float*)d_in[4];
    const float* b1     = (const float*)d_in[5];
    const float* W2     = (const float*)d_in[6];
    const float* a_src2 = (const float*)d_in[7];
    const float* a_dst2 = (const float*)d_in[8];
    const float* b2     = (const float*)d_in[9];
    float* out = (float*)d_out;

    char* w = (char*)d_ws;
    size_t off = 0;
    auto alloc = [&](size_t bytes) {
        void* p = w + off; off += (bytes + 255) & ~(size_t)255; return p;
    };
    ushort_t* h1       = (ushort_t*)alloc((size_t)N_NODES * C1 * 2);
    ushort_t* out1     = (ushort_t*)alloc((size_t)N_NODES * C1 * 2);
    float*    as1      = (float*)   alloc((size_t)N_NODES * 4 * 4);
    float*    ad1      = (float*)   alloc((size_t)N_NODES * 4 * 4);
    float*    h2       = (float*)   alloc((size_t)N_NODES * 4);
    float*    as2      = (float*)   alloc((size_t)N_NODES * 4);
    float*    ad2      = (float*)   alloc((size_t)N_NODES * 4);
    int*      row_start= (int*)     alloc((size_t)(N_NODES + 1) * 4);
    int*      deg      = (int*)     alloc((size_t)N_NODES * 4);
    int*      cursor   = (int*)     alloc((size_t)N_NODES * 4);
    int*      edge_src = (int*)     alloc((size_t)ET * 4);
    int*      flag64   = (int*)     alloc(4);

    k_init_deg<<<(N_NODES + 255) / 256, 256, 0, stream>>>(ei, deg, flag64);
    k_count<<<(N_EDGES + 255) / 256, 256, 0, stream>>>(ei, flag64, deg);
    k_scan<<<1, 1024, 0, stream>>>(deg, row_start, cursor);
    k_scatter<<<(ET + 255) / 256, 256, 0, stream>>>(ei, flag64, cursor, edge_src);

    dim3 g1((N_NODES + 63) / 64, C1 / 64);
    k_gemm1<<<g1, 256, 0, stream>>>(x, W1, h1);
    k_alpha1<<<N_NODES / 4, 256, 0, stream>>>(h1, a_src1, a_dst1, as1, ad1);
    k_agg1<<<N_NODES / 4, 256, 0, stream>>>(h1, as1, ad1, row_start, edge_src, b1, out1);
    k_l2a<<<N_NODES / 4, 256, 0, stream>>>(out1, W2, a_src2, a_dst2, h2, as2, ad2);
    k_agg2<<<N_NODES / 4, 256, 0, stream>>>(h2, as2, ad2, row_start, edge_src, b2, out);
}

// Round 4
// 342.364 us; speedup vs baseline: 1.2914x; 1.1857x over previous
//
#include <hip/hip_runtime.h>
#include <hip/hip_bf16.h>

#define N_NODES 50000
#define N_EDGES 800000
#define ET      (N_EDGES + N_NODES)   // edges + self loops = 850000
#define IN_DIM  128
#define HID     64
#define HEADS   4
#define C1      (HEADS * HID)         // 256
#define NEG_SLOPE 0.2f

typedef unsigned short ushort_t;

__device__ __forceinline__ float asf(unsigned int u) {
    union { unsigned int i; float f; } c; c.i = u; return c.f;
}
__device__ __forceinline__ float bf2f(ushort_t u) {
    return asf(((unsigned int)u) << 16);
}
__device__ __forceinline__ ushort_t f2bf(float f) {
    union { float f; unsigned int i; } c; c.f = f;
    unsigned int r = c.i + 0x7fffu + ((c.i >> 16) & 1u);   // RNE
    return (ushort_t)(r >> 16);
}
__device__ __forceinline__ float lrelu(float x) { return x > 0.f ? x : NEG_SLOPE * x; }

__device__ __forceinline__ float wave_sum(float v) {
    #pragma unroll
    for (int off = 32; off > 0; off >>= 1) v += __shfl_xor(v, off, 64);
    return v;
}

__device__ __forceinline__ int load_idx(const int* ei, int elem, int is64) {
    return is64 ? ei[2 * elem] : ei[elem];   // little-endian low word
}

// ---------------- CSR build ----------------
__global__ void k_init_deg(const int* __restrict__ ei, int* __restrict__ deg,
                           int* __restrict__ flag) {
    int i = blockIdx.x * 256 + threadIdx.x;
    if (i < N_NODES) deg[i] = 1;   // self-loop
    if (i == 0) {                  // int64 edge_index detector (high words all 0)
        int z = 1;
        for (int k = 1; k < 64; k += 2) if (ei[k] != 0) z = 0;
        *flag = z;
    }
}

__global__ void k_count(const int* __restrict__ ei, const int* __restrict__ flag,
                        int* __restrict__ deg) {
    int i = blockIdx.x * 256 + threadIdx.x;
    if (i < N_EDGES) {
        int d = load_idx(ei, N_EDGES + i, *flag);
        atomicAdd(&deg[d], 1);
    }
}

__global__ __launch_bounds__(1024) void k_scan(const int* __restrict__ deg,
                                               int* __restrict__ row_start,
                                               int* __restrict__ cursor) {
    __shared__ int wsum[16];
    __shared__ int srun;
    int tid = threadIdx.x, lane = tid & 63, wid = tid >> 6;
    if (tid == 0) srun = 0;
    __syncthreads();
    const int nchunk = (N_NODES + 1023) / 1024;
    for (int c = 0; c < nchunk; ++c) {
        int idx = c * 1024 + tid;
        int v = (idx < N_NODES) ? deg[idx] : 0;
        int x = v;
        #pragma unroll
        for (int off = 1; off < 64; off <<= 1) {
            int t = __shfl_up(x, off, 64);
            if (lane >= off) x += t;
        }
        if (lane == 63) wsum[wid] = x;
        __syncthreads();
        if (tid < 16) {
            int t = wsum[tid];
            int y = t;
            #pragma unroll
            for (int off = 1; off < 16; off <<= 1) {
                int u = __shfl_up(y, off, 64);
                if (tid >= off) y += u;
            }
            int base = srun;
            wsum[tid] = base + y - t;       // exclusive prefix for this wave
            if (tid == 15) srun = base + y; // running total
        }
        __syncthreads();
        int excl = wsum[wid] + (x - v);
        if (idx < N_NODES) { row_start[idx] = excl; cursor[idx] = excl; }
    }
    if (tid == 0) row_start[N_NODES] = srun;
}

__global__ void k_scatter(const int* __restrict__ ei, const int* __restrict__ flag,
                          int* __restrict__ cursor, int* __restrict__ edge_src) {
    int i = blockIdx.x * 256 + threadIdx.x;
    if (i >= ET) return;
    int s, d;
    if (i < N_EDGES) {
        int f = *flag;
        s = load_idx(ei, i, f);
        d = load_idx(ei, N_EDGES + i, f);
    } else {
        s = d = i - N_EDGES;
    }
    int pos = atomicAdd(&cursor[d], 1);
    edge_src[pos] = s;
}

// ---------------- Layer 1 GEMM + fused attention-logit epilogue ----------------
// blockIdx.y == head: the 64 output cols of this block are exactly one head,
// so as1/ad1 for that head reduce entirely inside the block (16-lane shuffle).
__global__ __launch_bounds__(256) void k_gemm1(const float* __restrict__ x,
                                               const float* __restrict__ W1,
                                               const float* __restrict__ a_src1,
                                               const float* __restrict__ a_dst1,
                                               ushort_t* __restrict__ h1,
                                               float* __restrict__ as1,
                                               float* __restrict__ ad1) {
    __shared__ float As[64][68];   // padded: kills 4-way bank conflict
    __shared__ float Bs[64][64];
    int tid = threadIdx.x;
    int tx = tid & 15, ty = tid >> 4;
    int row0 = blockIdx.x * 64, col0 = blockIdx.y * 64;
    float acc[4][4] = {{0.f}};
    for (int kc = 0; kc < 2; ++kc) {
        #pragma unroll
        for (int it = 0; it < 4; ++it) {
            int e = (it * 256 + tid) * 4;
            int r = e >> 6, k = e & 63;
            int row = row0 + r;
            float4 av = make_float4(0.f, 0.f, 0.f, 0.f);
            if (row < N_NODES) av = *(const float4*)(x + row * IN_DIM + kc * 64 + k);
            *(float4*)&As[r][k] = av;
            *(float4*)&Bs[r][k] = *(const float4*)(W1 + (kc * 64 + r) * C1 + col0 + k);
        }
        __syncthreads();
        #pragma unroll 4
        for (int k = 0; k < 64; k += 4) {
            float a[4][4], b[4][4];
            #pragma unroll
            for (int i2 = 0; i2 < 4; ++i2) *(float4*)a[i2] = *(const float4*)&As[ty * 4 + i2][k];
            #pragma unroll
            for (int kk = 0; kk < 4; ++kk) *(float4*)b[kk] = *(const float4*)&Bs[k + kk][tx * 4];
            #pragma unroll
            for (int i2 = 0; i2 < 4; ++i2)
                #pragma unroll
                for (int j = 0; j < 4; ++j)
                    acc[i2][j] += a[i2][0] * b[0][j] + a[i2][1] * b[1][j]
                                + a[i2][2] * b[2][j] + a[i2][3] * b[3][j];
        }
        __syncthreads();
    }
    // h1 store
    #pragma unroll
    for (int i2 = 0; i2 < 4; ++i2) {
        int row = row0 + ty * 4 + i2;
        if (row < N_NODES) {
            ushort4 hv;
            hv.x = f2bf(acc[i2][0]); hv.y = f2bf(acc[i2][1]);
            hv.z = f2bf(acc[i2][2]); hv.w = f2bf(acc[i2][3]);
            *(ushort4*)&h1[row * C1 + col0 + tx * 4] = hv;
        }
    }
    // fused alpha epilogue: per-row dot with a_src/a_dst for this head
    float4 asv = *(const float4*)(a_src1 + col0 + tx * 4);
    float4 adv = *(const float4*)(a_dst1 + col0 + tx * 4);
    #pragma unroll
    for (int i2 = 0; i2 < 4; ++i2) {
        float ps = acc[i2][0] * asv.x + acc[i2][1] * asv.y
                 + acc[i2][2] * asv.z + acc[i2][3] * asv.w;
        float pd = acc[i2][0] * adv.x + acc[i2][1] * adv.y
                 + acc[i2][2] * adv.z + acc[i2][3] * adv.w;
        #pragma unroll
        for (int off = 1; off < 16; off <<= 1) {
            ps += __shfl_xor(ps, off, 64);
            pd += __shfl_xor(pd, off, 64);
        }
        int row = row0 + ty * 4 + i2;
        if (tx == 0 && row < N_NODES) {
            as1[row * 4 + blockIdx.y] = ps;
            ad1[row * 4 + blockIdx.y] = pd;
        }
    }
}

// ---------------- Layer 1 softmax-agg + bias + ReLU + fused layer-2 projection ----------------
// No max pass (logits bounded; softmax shift-invariant). Weights computed once
// per edge (lane-parallel), staged in per-wave LDS; gather loop unrolled x4 with
// v_readlane scalar indices for MLP. out1 never materialized: the layer-2
// GEMV (256->1) happens in registers; emits pk[node]={as2,h2} and ad2[node].
__global__ __launch_bounds__(256) void k_agg1(const ushort_t* __restrict__ h1,
                                              const float* __restrict__ as1,
                                              const float* __restrict__ ad1,
                                              const int* __restrict__ row_start,
                                              const int* __restrict__ edge_src,
                                              const float* __restrict__ b1,
                                              const float* __restrict__ W2,
                                              const float* __restrict__ a_src2,
                                              const float* __restrict__ a_dst2,
                                              float2* __restrict__ pk,
                                              float* __restrict__ ad2) {
    __shared__ float wbuf[4][64][4];   // [wave][chunk-pos][head]
    int lane = threadIdx.x & 63;
    int wid  = threadIdx.x >> 6;
    int node = blockIdx.x * 4 + wid;
    int rs = row_start[node], re = row_start[node + 1];
    float4 ad = *(const float4*)&ad1[node * 4];
    const int head = lane >> 4;

    float4 acc = make_float4(0.f, 0.f, 0.f, 0.f);
    float4 den = make_float4(0.f, 0.f, 0.f, 0.f);

    for (int base = rs; base < re; base += 64) {
        int i = base + lane;
        int s_l = 0;
        float4 w = make_float4(0.f, 0.f, 0.f, 0.f);
        if (i < re) {
            s_l = edge_src[i];
            float4 av = *(const float4*)&as1[s_l * 4];
            w.x = __expf(lrelu(av.x + ad.x));
            w.y = __expf(lrelu(av.y + ad.y));
            w.z = __expf(lrelu(av.z + ad.z));
            w.w = __expf(lrelu(av.w + ad.w));
        }
        den.x += w.x; den.y += w.y; den.z += w.z; den.w += w.w;
        *(float4*)&wbuf[wid][lane][0] = w;
        int m = re - base; if (m > 64) m = 64;
        int j = 0;
        for (; j + 4 <= m; j += 4) {
            int s0 = __builtin_amdgcn_readlane(s_l, j + 0);
            int s1 = __builtin_amdgcn_readlane(s_l, j + 1);
            int s2 = __builtin_amdgcn_readlane(s_l, j + 2);
            int s3 = __builtin_amdgcn_readlane(s_l, j + 3);
            uint2 p0 = *(const uint2*)(h1 + (size_t)s0 * C1 + lane * 4);
            uint2 p1 = *(const uint2*)(h1 + (size_t)s1 * C1 + lane * 4);
            uint2 p2 = *(const uint2*)(h1 + (size_t)s2 * C1 + lane * 4);
            uint2 p3 = *(const uint2*)(h1 + (size_t)s3 * C1 + lane * 4);
            float g0 = wbuf[wid][j + 0][head];
            float g1 = wbuf[wid][j + 1][head];
            float g2 = wbuf[wid][j + 2][head];
            float g3 = wbuf[wid][j + 3][head];
            acc.x += g0 * asf(p0.x << 16);
            acc.y += g0 * asf(p0.x & 0xffff0000u);
            acc.z += g0 * asf(p0.y << 16);
            acc.w += g0 * asf(p0.y & 0xffff0000u);
            acc.x += g1 * asf(p1.x << 16);
            acc.y += g1 * asf(p1.x & 0xffff0000u);
            acc.z += g1 * asf(p1.y << 16);
            acc.w += g1 * asf(p1.y & 0xffff0000u);
            acc.x += g2 * asf(p2.x << 16);
            acc.y += g2 * asf(p2.x & 0xffff0000u);
            acc.z += g2 * asf(p2.y << 16);
            acc.w += g2 * asf(p2.y & 0xffff0000u);
            acc.x += g3 * asf(p3.x << 16);
            acc.y += g3 * asf(p3.x & 0xffff0000u);
            acc.z += g3 * asf(p3.y << 16);
            acc.w += g3 * asf(p3.y & 0xffff0000u);
        }
        for (; j < m; ++j) {
            int s0 = __builtin_amdgcn_readlane(s_l, j);
            uint2 p0 = *(const uint2*)(h1 + (size_t)s0 * C1 + lane * 4);
            float g0 = wbuf[wid][j][head];
            acc.x += g0 * asf(p0.x << 16);
            acc.y += g0 * asf(p0.x & 0xffff0000u);
            acc.z += g0 * asf(p0.y << 16);
            acc.w += g0 * asf(p0.y & 0xffff0000u);
        }
    }

    float d0 = wave_sum(den.x), d1 = wave_sum(den.y);
    float d2 = wave_sum(den.z), d3 = wave_sum(den.w);
    float dh = head == 0 ? d0 : head == 1 ? d1 : head == 2 ? d2 : d3;
    float inv = 1.f / (dh + 1e-16f);
    float4 bv = *(const float4*)&b1[lane * 4];
    float o0 = fmaxf(acc.x * inv + bv.x, 0.f);
    float o1 = fmaxf(acc.y * inv + bv.y, 0.f);
    float o2 = fmaxf(acc.z * inv + bv.z, 0.f);
    float o3 = fmaxf(acc.w * inv + bv.w, 0.f);
    // fused layer-2 projection (256 -> 1)
    float4 wv = *(const float4*)&W2[lane * 4];
    float sum = o0 * wv.x + o1 * wv.y + o2 * wv.z + o3 * wv.w;
    sum = wave_sum(sum);
    if (lane == 0) {
        float2 p; p.x = sum * a_src2[0]; p.y = sum;
        pk[node]  = p;
        ad2[node] = sum * a_dst2[0];
    }
}

// ---------------- Layer 2 softmax-agg + sigmoid (no max pass, packed gather) ----------------
__global__ __launch_bounds__(256) void k_agg2(const float2* __restrict__ pk,
                                              const float* __restrict__ ad2,
                                              const int* __restrict__ row_start,
                                              const int* __restrict__ edge_src,
                                              const float* __restrict__ b2,
                                              float* __restrict__ outp) {
    int lane = threadIdx.x & 63;
    int node = blockIdx.x * 4 + (threadIdx.x >> 6);
    int rs = row_start[node], re = row_start[node + 1];
    float adv = ad2[node];
    float se = 0.f, wsm = 0.f;
    for (int i = rs + lane; i < re; i += 64) {
        int s = edge_src[i];
        float2 p = pk[s];            // one 8B gather: {as2, h2}
        float w = __expf(lrelu(p.x + adv));
        se += w; wsm += w * p.y;
    }
    se = wave_sum(se); wsm = wave_sum(wsm);
    if (lane == 0) {
        float v = wsm / (se + 1e-16f) + b2[0];
        outp[node] = 1.f / (1.f + __expf(-v));
    }
}

extern "C" void kernel_launch(void* const* d_in, const int* in_sizes, int n_in,
                              void* d_out, int out_size, void* d_ws, size_t ws_size,
                              hipStream_t stream) {
    (void)in_sizes; (void)n_in; (void)out_size; (void)ws_size;
    const float* x      = (const float*)d_in[0];
    const int*   ei     = (const int*)  d_in[1];
    const float* W1     = (const float*)d_in[2];
    const float* a_src1 = (const float*)d_in[3];
    const float* a_dst1 = (const float*)d_in[4];
    const float* b1     = (const float*)d_in[5];
    const float* W2     = (const float*)d_in[6];
    const float* a_src2 = (const float*)d_in[7];
    const float* a_dst2 = (const float*)d_in[8];
    const float* b2     = (const float*)d_in[9];
    float* out = (float*)d_out;

    char* w = (char*)d_ws;
    size_t off = 0;
    auto alloc = [&](size_t bytes) {
        void* p = w + off; off += (bytes + 255) & ~(size_t)255; return p;
    };
    ushort_t* h1       = (ushort_t*)alloc((size_t)N_NODES * C1 * 2);
    float*    as1      = (float*)   alloc((size_t)N_NODES * 4 * 4);
    float*    ad1      = (float*)   alloc((size_t)N_NODES * 4 * 4);
    float2*   pk       = (float2*)  alloc((size_t)N_NODES * 8);
    float*    ad2      = (float*)   alloc((size_t)N_NODES * 4);
    int*      row_start= (int*)     alloc((size_t)(N_NODES + 1) * 4);
    int*      deg      = (int*)     alloc((size_t)N_NODES * 4);
    int*      cursor   = (int*)     alloc((size_t)N_NODES * 4);
    int*      edge_src = (int*)     alloc((size_t)ET * 4);
    int*      flag64   = (int*)     alloc(4);

    k_init_deg<<<(N_NODES + 255) / 256, 256, 0, stream>>>(ei, deg, flag64);
    k_count<<<(N_EDGES + 255) / 256, 256, 0, stream>>>(ei, flag64, deg);
    k_scan<<<1, 1024, 0, stream>>>(deg, row_start, cursor);
    k_scatter<<<(ET + 255) / 256, 256, 0, stream>>>(ei, flag64, cursor, edge_src);

    dim3 g1((N_NODES + 63) / 64, C1 / 64);
    k_gemm1<<<g1, 256, 0, stream>>>(x, W1, a_src1, a_dst1, h1, as1, ad1);
    k_agg1<<<N_NODES / 4, 256, 0, stream>>>(h1, as1, ad1, row_start, edge_src,
                                            b1, W2, a_src2, a_dst2, pk, ad2);
    k_agg2<<<N_NODES / 4, 256, 0, stream>>>(pk, ad2, row_start, edge_src, b2, out);
}